// Round 1
// baseline (449.520 us; speedup 1.0000x reference)
//
#include <hip/hip_runtime.h>
#include <hip/hip_bf16.h>
#include <stdint.h>

#define E_EDGES 80000
#define N_NODES 10000
#define HD      64
#define DDIST   128
#define DIN     256
#define NCOEF   49
#define W3OUT   224   // M0(7) * C_SPH(32)

// ---------------------------------------------------------------------------
// Kernel A: per-edge MLP.  8 edges per wave, 4 waves per block (32 edges).
// lanes = output channels; x stored transposed in LDS [k][edge] so the GEMM
// inner loop is: coalesced W row load (global, L2-hot) x broadcast-LDS x.
// Writes y3[e][224] = (silu(LN(silu(LN(x@W1+b1))@W2+b2))@W3 + b3) / RESCALE.
// ---------------------------------------------------------------------------
__global__ __launch_bounds__(256) void k_mlp(
    const int* __restrict__ an, const int* __restrict__ ei,
    const float* __restrict__ ed,
    const float* __restrict__ semb, const float* __restrict__ temb,
    const float* __restrict__ W1, const float* __restrict__ b1,
    const float* __restrict__ g1, const float* __restrict__ be1,
    const float* __restrict__ W2, const float* __restrict__ b2,
    const float* __restrict__ g2, const float* __restrict__ be2,
    const float* __restrict__ W3, const float* __restrict__ b3,
    float* __restrict__ y3)
{
    __shared__ float xT[4][DIN * 8];
    __shared__ float hT[4][HD * 8];
    __shared__ float h2T[4][HD * 8];
    const int tid  = threadIdx.x;
    const int wave = tid >> 6;
    const int lane = tid & 63;
    const int e0   = blockIdx.x * 32 + wave * 8;
    float* __restrict__ xw  = xT[wave];
    float* __restrict__ hw  = hT[wave];
    float* __restrict__ h2w = h2T[wave];

    // stage x = [edge_distance(128) | src_emb(64) | tgt_emb(64)], layout [k][ep]
    #pragma unroll
    for (int ep = 0; ep < 8; ep++) {
        const int e = e0 + ep;
        xw[lane * 8 + ep]        = ed[e * DDIST + lane];
        xw[(64 + lane) * 8 + ep] = ed[e * DDIST + 64 + lane];
        const int sn = ei[e];
        const int tn = ei[E_EDGES + e];
        xw[(128 + lane) * 8 + ep] = semb[an[sn] * HD + lane];
        xw[(192 + lane) * 8 + ep] = temb[an[tn] * HD + lane];
    }
    __syncthreads();

    // ---- layer 1 -----------------------------------------------------------
    float acc[8];
    #pragma unroll
    for (int ep = 0; ep < 8; ep++) acc[ep] = 0.f;
    #pragma unroll 4
    for (int k = 0; k < DIN; k++) {
        const float w  = W1[k * HD + lane];
        const float4 xa = *(const float4*)(xw + k * 8);
        const float4 xb = *(const float4*)(xw + k * 8 + 4);
        acc[0] = fmaf(w, xa.x, acc[0]); acc[1] = fmaf(w, xa.y, acc[1]);
        acc[2] = fmaf(w, xa.z, acc[2]); acc[3] = fmaf(w, xa.w, acc[3]);
        acc[4] = fmaf(w, xb.x, acc[4]); acc[5] = fmaf(w, xb.y, acc[5]);
        acc[6] = fmaf(w, xb.z, acc[6]); acc[7] = fmaf(w, xb.w, acc[7]);
    }
    {
        const float bb = b1[lane], gg = g1[lane], be = be1[lane];
        #pragma unroll
        for (int ep = 0; ep < 8; ep++) {
            float h = acc[ep] + bb;
            float s = h, s2 = h * h;
            #pragma unroll
            for (int off = 32; off > 0; off >>= 1) {
                s  += __shfl_xor(s,  off, 64);
                s2 += __shfl_xor(s2, off, 64);
            }
            const float mu  = s * (1.f / 64.f);
            const float var = fmaxf(s2 * (1.f / 64.f) - mu * mu, 0.f);
            const float t   = (h - mu) * rsqrtf(var + 1e-5f) * gg + be;
            hw[lane * 8 + ep] = t / (1.f + expf(-t));   // silu
        }
    }
    __syncthreads();

    // ---- layer 2 -----------------------------------------------------------
    #pragma unroll
    for (int ep = 0; ep < 8; ep++) acc[ep] = 0.f;
    #pragma unroll 4
    for (int k = 0; k < HD; k++) {
        const float w  = W2[k * HD + lane];
        const float4 xa = *(const float4*)(hw + k * 8);
        const float4 xb = *(const float4*)(hw + k * 8 + 4);
        acc[0] = fmaf(w, xa.x, acc[0]); acc[1] = fmaf(w, xa.y, acc[1]);
        acc[2] = fmaf(w, xa.z, acc[2]); acc[3] = fmaf(w, xa.w, acc[3]);
        acc[4] = fmaf(w, xb.x, acc[4]); acc[5] = fmaf(w, xb.y, acc[5]);
        acc[6] = fmaf(w, xb.z, acc[6]); acc[7] = fmaf(w, xb.w, acc[7]);
    }
    {
        const float bb = b2[lane], gg = g2[lane], be = be2[lane];
        #pragma unroll
        for (int ep = 0; ep < 8; ep++) {
            float h = acc[ep] + bb;
            float s = h, s2 = h * h;
            #pragma unroll
            for (int off = 32; off > 0; off >>= 1) {
                s  += __shfl_xor(s,  off, 64);
                s2 += __shfl_xor(s2, off, 64);
            }
            const float mu  = s * (1.f / 64.f);
            const float var = fmaxf(s2 * (1.f / 64.f) - mu * mu, 0.f);
            const float t   = (h - mu) * rsqrtf(var + 1e-5f) * gg + be;
            h2w[lane * 8 + ep] = t / (1.f + expf(-t));
        }
    }
    __syncthreads();

    // ---- layer 3 (224 outputs = 4 chunks of 64 lanes) ----------------------
    #pragma unroll
    for (int chunk = 0; chunk < 4; chunk++) {
        const int ch = chunk * 64 + lane;
        const bool valid = (ch < W3OUT);
        float a2[8];
        #pragma unroll
        for (int ep = 0; ep < 8; ep++) a2[ep] = 0.f;
        #pragma unroll 4
        for (int k = 0; k < HD; k++) {
            const float w  = valid ? W3[k * W3OUT + ch] : 0.f;
            const float4 xa = *(const float4*)(h2w + k * 8);
            const float4 xb = *(const float4*)(h2w + k * 8 + 4);
            a2[0] = fmaf(w, xa.x, a2[0]); a2[1] = fmaf(w, xa.y, a2[1]);
            a2[2] = fmaf(w, xa.z, a2[2]); a2[3] = fmaf(w, xa.w, a2[3]);
            a2[4] = fmaf(w, xb.x, a2[4]); a2[5] = fmaf(w, xb.y, a2[5]);
            a2[6] = fmaf(w, xb.z, a2[6]); a2[7] = fmaf(w, xb.w, a2[7]);
        }
        if (valid) {
            const float bb3 = b3[ch];
            #pragma unroll
            for (int ep = 0; ep < 8; ep++)
                y3[(e0 + ep) * W3OUT + ch] = (a2[ep] + bb3) * (1.0f / 5.862f);
        }
    }
}

// ---------------------------------------------------------------------------
// CSR build: count -> exclusive scan (single block) -> scatter
// ---------------------------------------------------------------------------
__global__ void k_count(const int* __restrict__ ei, int* __restrict__ cnt) {
    const int e = blockIdx.x * 256 + threadIdx.x;
    if (e < E_EDGES) atomicAdd(&cnt[ei[E_EDGES + e]], 1);
}

__global__ __launch_bounds__(1024) void k_scan(const int* __restrict__ cnt,
                                               int* __restrict__ offs,
                                               int* __restrict__ cursor) {
    __shared__ int buf[1024];
    __shared__ int carry_s;
    const int tid = threadIdx.x;
    if (tid == 0) carry_s = 0;
    __syncthreads();
    for (int base = 0; base < N_NODES; base += 1024) {
        const int idx = base + tid;
        const int v = (idx < N_NODES) ? cnt[idx] : 0;
        buf[tid] = v;
        __syncthreads();
        for (int off = 1; off < 1024; off <<= 1) {
            int t = 0;
            if (tid >= off) t = buf[tid - off];
            __syncthreads();
            buf[tid] += t;
            __syncthreads();
        }
        const int carry = carry_s;
        const int excl = carry + buf[tid] - v;
        if (idx < N_NODES) { offs[idx] = excl; cursor[idx] = excl; }
        __syncthreads();
        if (tid == 0) carry_s = carry + buf[1023];
        __syncthreads();
    }
    if (tid == 0) offs[N_NODES] = carry_s;
}

__global__ void k_scatter(const int* __restrict__ ei, int* __restrict__ cursor,
                          int* __restrict__ eids) {
    const int e = blockIdx.x * 256 + threadIdx.x;
    if (e < E_EDGES) {
        const int pos = atomicAdd(&cursor[ei[E_EDGES + e]], 1);
        eids[pos] = e;
    }
}

// ---------------------------------------------------------------------------
// Kernel B: per-node reduction.
// out[n,i,c] = sum_{e in node n} sum_{l=0..6} wig[e, i, l*l+l] * y3[e, l, c]
// Block = 256 threads: c = tid&31, row group rr = tid>>5; thread accumulates
// rows i = 8*r + rr (r = 0..6) in registers, single coalesced store at end.
// ---------------------------------------------------------------------------
__global__ __launch_bounds__(256) void k_out(
    const float* __restrict__ wig, const float* __restrict__ y3,
    const int* __restrict__ offs, const int* __restrict__ eids,
    float* __restrict__ out)
{
    __shared__ float wl[NCOEF * 8];   // [i][l], l padded to 8
    __shared__ float yl[W3OUT];       // [l][c]
    const int n   = blockIdx.x;
    const int tid = threadIdx.x;
    const int c   = tid & 31;
    const int rr  = tid >> 5;         // 0..7
    const int beg = offs[n];
    const int end = offs[n + 1];

    float acc[7];
    #pragma unroll
    for (int r = 0; r < 7; r++) acc[r] = 0.f;

    for (int ie = beg; ie < end; ie++) {
        const int e = eids[ie];
        if (tid < W3OUT) yl[tid] = y3[e * W3OUT + tid];
        for (int t = tid; t < NCOEF * 7; t += 256) {
            const int i = t / 7;
            const int l = t - i * 7;
            wl[i * 8 + l] = wig[(size_t)e * (NCOEF * NCOEF) + i * NCOEF + l * (l + 1)];
        }
        __syncthreads();

        float yr[7];
        #pragma unroll
        for (int l = 0; l < 7; l++) yr[l] = yl[l * 32 + c];
        #pragma unroll
        for (int r = 0; r < 7; r++) {
            const int i = r * 8 + rr;
            if (i < NCOEF) {
                const float4 wa = *(const float4*)(wl + i * 8);
                const float4 wb = *(const float4*)(wl + i * 8 + 4);
                acc[r] += wa.x * yr[0] + wa.y * yr[1] + wa.z * yr[2] + wa.w * yr[3]
                        + wb.x * yr[4] + wb.y * yr[5] + wb.z * yr[6];
            }
        }
        __syncthreads();
    }

    #pragma unroll
    for (int r = 0; r < 7; r++) {
        const int i = r * 8 + rr;
        if (i < NCOEF) out[(size_t)n * (NCOEF * 32) + i * 32 + c] = acc[r];
    }
}

// ---------------------------------------------------------------------------
extern "C" void kernel_launch(void* const* d_in, const int* in_sizes, int n_in,
                              void* d_out, int out_size, void* d_ws, size_t ws_size,
                              hipStream_t stream)
{
    const int*   an   = (const int*)  d_in[0];
    const int*   ei   = (const int*)  d_in[1];
    const float* ed   = (const float*)d_in[2];
    const float* wig  = (const float*)d_in[3];
    const float* semb = (const float*)d_in[4];
    const float* temb = (const float*)d_in[5];
    const float* W1   = (const float*)d_in[6];
    const float* b1   = (const float*)d_in[7];
    const float* g1   = (const float*)d_in[8];
    const float* be1  = (const float*)d_in[9];
    const float* W2   = (const float*)d_in[10];
    const float* b2   = (const float*)d_in[11];
    const float* g2   = (const float*)d_in[12];
    const float* be2  = (const float*)d_in[13];
    const float* W3   = (const float*)d_in[14];
    const float* b3   = (const float*)d_in[15];
    float* out = (float*)d_out;

    char* ws = (char*)d_ws;
    const size_t y3_bytes = (size_t)E_EDGES * W3OUT * sizeof(float); // 71.68 MB
    float* y3     = (float*)ws;
    int*   cnt    = (int*)(ws + y3_bytes);
    int*   offs   = cnt + N_NODES;
    int*   cursor = offs + N_NODES + 1;
    int*   eids   = cursor + N_NODES;
    const size_t need = y3_bytes +
        sizeof(int) * ((size_t)N_NODES + (N_NODES + 1) + N_NODES + E_EDGES);
    if (ws_size < need) return;  // scratch too small: fail validation cleanly

    hipMemsetAsync(cnt, 0, N_NODES * sizeof(int), stream);
    k_mlp<<<E_EDGES / 32, 256, 0, stream>>>(an, ei, ed, semb, temb,
                                            W1, b1, g1, be1,
                                            W2, b2, g2, be2, W3, b3, y3);
    k_count<<<(E_EDGES + 255) / 256, 256, 0, stream>>>(ei, cnt);
    k_scan<<<1, 1024, 0, stream>>>(cnt, offs, cursor);
    k_scatter<<<(E_EDGES + 255) / 256, 256, 0, stream>>>(ei, cursor, eids);
    k_out<<<N_NODES, 256, 0, stream>>>(wig, y3, offs, eids, out);
}

// Round 2
// 434.244 us; speedup vs baseline: 1.0352x; 1.0352x over previous
//
#include <hip/hip_runtime.h>
#include <hip/hip_bf16.h>
#include <stdint.h>

#define E_EDGES 80000
#define N_NODES 10000
#define HD      64
#define DDIST   128
#define DIN     256
#define NCOEF   49
#define W3OUT   224   // M0(7) * C_SPH(32)
#define WROW    2401  // 49*49

// needed wigner columns: l*(l+1) for l=0..6 -> {0,2,6,12,20,30,42}
#define WMASK ((1ull<<0)|(1ull<<2)|(1ull<<6)|(1ull<<12)|(1ull<<20)|(1ull<<30)|(1ull<<42))

// ---------------------------------------------------------------------------
// Kernel A: per-edge MLP.  8 edges per wave, 4 waves per block (32 edges).
// (unchanged from round 1)
// ---------------------------------------------------------------------------
__global__ __launch_bounds__(256) void k_mlp(
    const int* __restrict__ an, const int* __restrict__ ei,
    const float* __restrict__ ed,
    const float* __restrict__ semb, const float* __restrict__ temb,
    const float* __restrict__ W1, const float* __restrict__ b1,
    const float* __restrict__ g1, const float* __restrict__ be1,
    const float* __restrict__ W2, const float* __restrict__ b2,
    const float* __restrict__ g2, const float* __restrict__ be2,
    const float* __restrict__ W3, const float* __restrict__ b3,
    float* __restrict__ y3)
{
    __shared__ float xT[4][DIN * 8];
    __shared__ float hT[4][HD * 8];
    __shared__ float h2T[4][HD * 8];
    const int tid  = threadIdx.x;
    const int wave = tid >> 6;
    const int lane = tid & 63;
    const int e0   = blockIdx.x * 32 + wave * 8;
    float* __restrict__ xw  = xT[wave];
    float* __restrict__ hw  = hT[wave];
    float* __restrict__ h2w = h2T[wave];

    #pragma unroll
    for (int ep = 0; ep < 8; ep++) {
        const int e = e0 + ep;
        xw[lane * 8 + ep]        = ed[e * DDIST + lane];
        xw[(64 + lane) * 8 + ep] = ed[e * DDIST + 64 + lane];
        const int sn = ei[e];
        const int tn = ei[E_EDGES + e];
        xw[(128 + lane) * 8 + ep] = semb[an[sn] * HD + lane];
        xw[(192 + lane) * 8 + ep] = temb[an[tn] * HD + lane];
    }
    __syncthreads();

    float acc[8];
    #pragma unroll
    for (int ep = 0; ep < 8; ep++) acc[ep] = 0.f;
    #pragma unroll 4
    for (int k = 0; k < DIN; k++) {
        const float w  = W1[k * HD + lane];
        const float4 xa = *(const float4*)(xw + k * 8);
        const float4 xb = *(const float4*)(xw + k * 8 + 4);
        acc[0] = fmaf(w, xa.x, acc[0]); acc[1] = fmaf(w, xa.y, acc[1]);
        acc[2] = fmaf(w, xa.z, acc[2]); acc[3] = fmaf(w, xa.w, acc[3]);
        acc[4] = fmaf(w, xb.x, acc[4]); acc[5] = fmaf(w, xb.y, acc[5]);
        acc[6] = fmaf(w, xb.z, acc[6]); acc[7] = fmaf(w, xb.w, acc[7]);
    }
    {
        const float bb = b1[lane], gg = g1[lane], be = be1[lane];
        #pragma unroll
        for (int ep = 0; ep < 8; ep++) {
            float h = acc[ep] + bb;
            float s = h, s2 = h * h;
            #pragma unroll
            for (int off = 32; off > 0; off >>= 1) {
                s  += __shfl_xor(s,  off, 64);
                s2 += __shfl_xor(s2, off, 64);
            }
            const float mu  = s * (1.f / 64.f);
            const float var = fmaxf(s2 * (1.f / 64.f) - mu * mu, 0.f);
            const float t   = (h - mu) * rsqrtf(var + 1e-5f) * gg + be;
            hw[lane * 8 + ep] = t / (1.f + expf(-t));
        }
    }
    __syncthreads();

    #pragma unroll
    for (int ep = 0; ep < 8; ep++) acc[ep] = 0.f;
    #pragma unroll 4
    for (int k = 0; k < HD; k++) {
        const float w  = W2[k * HD + lane];
        const float4 xa = *(const float4*)(hw + k * 8);
        const float4 xb = *(const float4*)(hw + k * 8 + 4);
        acc[0] = fmaf(w, xa.x, acc[0]); acc[1] = fmaf(w, xa.y, acc[1]);
        acc[2] = fmaf(w, xa.z, acc[2]); acc[3] = fmaf(w, xa.w, acc[3]);
        acc[4] = fmaf(w, xb.x, acc[4]); acc[5] = fmaf(w, xb.y, acc[5]);
        acc[6] = fmaf(w, xb.z, acc[6]); acc[7] = fmaf(w, xb.w, acc[7]);
    }
    {
        const float bb = b2[lane], gg = g2[lane], be = be2[lane];
        #pragma unroll
        for (int ep = 0; ep < 8; ep++) {
            float h = acc[ep] + bb;
            float s = h, s2 = h * h;
            #pragma unroll
            for (int off = 32; off > 0; off >>= 1) {
                s  += __shfl_xor(s,  off, 64);
                s2 += __shfl_xor(s2, off, 64);
            }
            const float mu  = s * (1.f / 64.f);
            const float var = fmaxf(s2 * (1.f / 64.f) - mu * mu, 0.f);
            const float t   = (h - mu) * rsqrtf(var + 1e-5f) * gg + be;
            h2w[lane * 8 + ep] = t / (1.f + expf(-t));
        }
    }
    __syncthreads();

    #pragma unroll
    for (int chunk = 0; chunk < 4; chunk++) {
        const int ch = chunk * 64 + lane;
        const bool valid = (ch < W3OUT);
        float a2[8];
        #pragma unroll
        for (int ep = 0; ep < 8; ep++) a2[ep] = 0.f;
        #pragma unroll 4
        for (int k = 0; k < HD; k++) {
            const float w  = valid ? W3[k * W3OUT + ch] : 0.f;
            const float4 xa = *(const float4*)(h2w + k * 8);
            const float4 xb = *(const float4*)(h2w + k * 8 + 4);
            a2[0] = fmaf(w, xa.x, a2[0]); a2[1] = fmaf(w, xa.y, a2[1]);
            a2[2] = fmaf(w, xa.z, a2[2]); a2[3] = fmaf(w, xa.w, a2[3]);
            a2[4] = fmaf(w, xb.x, a2[4]); a2[5] = fmaf(w, xb.y, a2[5]);
            a2[6] = fmaf(w, xb.z, a2[6]); a2[7] = fmaf(w, xb.w, a2[7]);
        }
        if (valid) {
            const float bb3 = b3[ch];
            #pragma unroll
            for (int ep = 0; ep < 8; ep++)
                y3[(e0 + ep) * W3OUT + ch] = (a2[ep] + bb3) * (1.0f / 5.862f);
        }
    }
}

// ---------------------------------------------------------------------------
// CSR build (unchanged)
// ---------------------------------------------------------------------------
__global__ void k_count(const int* __restrict__ ei, int* __restrict__ cnt) {
    const int e = blockIdx.x * 256 + threadIdx.x;
    if (e < E_EDGES) atomicAdd(&cnt[ei[E_EDGES + e]], 1);
}

__global__ __launch_bounds__(1024) void k_scan(const int* __restrict__ cnt,
                                               int* __restrict__ offs,
                                               int* __restrict__ cursor) {
    __shared__ int buf[1024];
    __shared__ int carry_s;
    const int tid = threadIdx.x;
    if (tid == 0) carry_s = 0;
    __syncthreads();
    for (int base = 0; base < N_NODES; base += 1024) {
        const int idx = base + tid;
        const int v = (idx < N_NODES) ? cnt[idx] : 0;
        buf[tid] = v;
        __syncthreads();
        for (int off = 1; off < 1024; off <<= 1) {
            int t = 0;
            if (tid >= off) t = buf[tid - off];
            __syncthreads();
            buf[tid] += t;
            __syncthreads();
        }
        const int carry = carry_s;
        const int excl = carry + buf[tid] - v;
        if (idx < N_NODES) { offs[idx] = excl; cursor[idx] = excl; }
        __syncthreads();
        if (tid == 0) carry_s = carry + buf[1023];
        __syncthreads();
    }
    if (tid == 0) offs[N_NODES] = carry_s;
}

__global__ void k_scatter(const int* __restrict__ ei, int* __restrict__ cursor,
                          int* __restrict__ eids) {
    const int e = blockIdx.x * 256 + threadIdx.x;
    if (e < E_EDGES) {
        const int pos = atomicAdd(&cursor[ei[E_EDGES + e]], 1);
        eids[pos] = e;
    }
}

// ---------------------------------------------------------------------------
// Kernel B: per-node reduction, round-2 rewrite.
//  * wigner row read as a fully-COALESCED dword stream (10 rounds x 256 thr),
//    needed columns selected via 64-bit mask + popcount slot.
//  * software pipeline: issue next edge's global loads into registers BEFORE
//    computing current edge from LDS; write regs->LDS after the read barrier.
// ---------------------------------------------------------------------------
__device__ __forceinline__ void kout_load(const float* __restrict__ wbase,
                                          const float* __restrict__ ybase,
                                          int tid, float v[10], float& yv)
{
    #pragma unroll
    for (int r = 0; r < 10; r++) {
        const int j = r * 256 + tid;
        v[r] = (j < WROW) ? wbase[j] : 0.f;
    }
    yv = (tid < W3OUT) ? ybase[tid] : 0.f;
}

__device__ __forceinline__ void kout_write(int tid, const float v[10], float yv,
                                           float* __restrict__ wl,
                                           float* __restrict__ yl)
{
    #pragma unroll
    for (int r = 0; r < 10; r++) {
        const unsigned j = r * 256 + tid;
        if (j < WROW) {
            const unsigned row = j / 49u;
            const unsigned col = j - row * 49u;
            if ((WMASK >> col) & 1ull) {
                const int slot = __popcll(WMASK & ((1ull << col) - 1ull));
                wl[row * 8 + slot] = v[r];
            }
        }
    }
    if (tid < W3OUT) yl[tid] = yv;
}

__global__ __launch_bounds__(256) void k_out(
    const float* __restrict__ wig, const float* __restrict__ y3,
    const int* __restrict__ offs, const int* __restrict__ eids,
    float* __restrict__ out)
{
    __shared__ float wl[NCOEF * 8];   // [i][slot], slot-padded to 8
    __shared__ float yl[W3OUT];       // [l*32 + c]
    const int n   = blockIdx.x;
    const int tid = threadIdx.x;
    const int c   = tid & 31;
    const int rr  = tid >> 5;         // 0..7
    const int beg = offs[n];
    const int end = offs[n + 1];

    float acc[7];
    #pragma unroll
    for (int r = 0; r < 7; r++) acc[r] = 0.f;

    float v[10];
    float yv;
    if (beg < end) {
        const int e = eids[beg];
        kout_load(wig + (size_t)e * WROW, y3 + (size_t)e * W3OUT, tid, v, yv);
        kout_write(tid, v, yv, wl, yl);
    }

    for (int ie = beg; ie < end; ie++) {
        __syncthreads();                       // staged LDS visible
        if (ie + 1 < end) {                    // issue next edge's loads early
            const int e2 = eids[ie + 1];
            kout_load(wig + (size_t)e2 * WROW, y3 + (size_t)e2 * W3OUT, tid, v, yv);
        }
        // compute current edge from LDS
        float yr[7];
        #pragma unroll
        for (int l = 0; l < 7; l++) yr[l] = yl[l * 32 + c];
        #pragma unroll
        for (int r = 0; r < 7; r++) {
            const int i = r * 8 + rr;
            if (i < NCOEF) {
                const float4 wa = *(const float4*)(wl + i * 8);
                const float4 wb = *(const float4*)(wl + i * 8 + 4);
                acc[r] += wa.x * yr[0] + wa.y * yr[1] + wa.z * yr[2] + wa.w * yr[3]
                        + wb.x * yr[4] + wb.y * yr[5] + wb.z * yr[6];
            }
        }
        __syncthreads();                       // everyone done reading LDS
        if (ie + 1 < end)
            kout_write(tid, v, yv, wl, yl);    // vm-wait + LDS write for next
    }

    #pragma unroll
    for (int r = 0; r < 7; r++) {
        const int i = r * 8 + rr;
        if (i < NCOEF) out[(size_t)n * (NCOEF * 32) + i * 32 + c] = acc[r];
    }
}

// ---------------------------------------------------------------------------
extern "C" void kernel_launch(void* const* d_in, const int* in_sizes, int n_in,
                              void* d_out, int out_size, void* d_ws, size_t ws_size,
                              hipStream_t stream)
{
    const int*   an   = (const int*)  d_in[0];
    const int*   ei   = (const int*)  d_in[1];
    const float* ed   = (const float*)d_in[2];
    const float* wig  = (const float*)d_in[3];
    const float* semb = (const float*)d_in[4];
    const float* temb = (const float*)d_in[5];
    const float* W1   = (const float*)d_in[6];
    const float* b1   = (const float*)d_in[7];
    const float* g1   = (const float*)d_in[8];
    const float* be1  = (const float*)d_in[9];
    const float* W2   = (const float*)d_in[10];
    const float* b2   = (const float*)d_in[11];
    const float* g2   = (const float*)d_in[12];
    const float* be2  = (const float*)d_in[13];
    const float* W3   = (const float*)d_in[14];
    const float* b3   = (const float*)d_in[15];
    float* out = (float*)d_out;

    char* ws = (char*)d_ws;
    const size_t y3_bytes = (size_t)E_EDGES * W3OUT * sizeof(float); // 71.68 MB
    float* y3     = (float*)ws;
    int*   cnt    = (int*)(ws + y3_bytes);
    int*   offs   = cnt + N_NODES;
    int*   cursor = offs + N_NODES + 1;
    int*   eids   = cursor + N_NODES;
    const size_t need = y3_bytes +
        sizeof(int) * ((size_t)N_NODES + (N_NODES + 1) + N_NODES + E_EDGES);
    if (ws_size < need) return;

    hipMemsetAsync(cnt, 0, N_NODES * sizeof(int), stream);
    k_mlp<<<E_EDGES / 32, 256, 0, stream>>>(an, ei, ed, semb, temb,
                                            W1, b1, g1, be1,
                                            W2, b2, g2, be2, W3, b3, y3);
    k_count<<<(E_EDGES + 255) / 256, 256, 0, stream>>>(ei, cnt);
    k_scan<<<1, 1024, 0, stream>>>(cnt, offs, cursor);
    k_scatter<<<(E_EDGES + 255) / 256, 256, 0, stream>>>(ei, cursor, eids);
    k_out<<<N_NODES, 256, 0, stream>>>(wig, y3, offs, eids, out);
}